// Round 4
// baseline (78.983 us; speedup 1.0000x reference)
//
#include <hip/hip_runtime.h>
#include <hip/hip_bf16.h>
#include <stdint.h>

// VQ: z (32,256,32,32) f32 NCHW, codebook (1024,256) f32
// out: z_q (8388608 f32, NCHW) + commit_loss (1 f32 at out[8388608])
//
// R4: R3 structure with the register-allocation bug fixed.
// 256 blocks x 512 thr (8 waves = 4 M-groups x 2 N-halves). Each wave:
// 32 rows of z as bf16 B-frags in regs, streams its codebook half (fragment-
// ordered bf16, pre-scaled by -2, built by k0) from L2/L1 with register
// double-buffering. ks-major MFMA for 4-chain ILP. Argmin via encoded-float
// min (S & ~0x3FF) | code; cross-half merge in LDS. Fused z_q gather + NCHW
// transpose epilogue; loss via sum(z^2) + sum(minS).
// VGPR budget ~233: needs 256-cap => amdgpu_waves_per_eu(2), NOT
// __launch_bounds__(512,2) which capped at 128 and spilled (R3 evidence:
// VGPR_Count=128, FETCH 51MB vs 23MB, cold dispatch 188us).

#define NPOS   32768
#define NCODE  1024
#define DIM    256

#define WS_CNORM_OFF 0
#define WS_CB_OFF    4096
#define WS_PART_OFF  (4096 + 1024 * 512)   // after 512KB cbfrag

typedef float f32x4 __attribute__((ext_vector_type(4)));
typedef short s16x8 __attribute__((ext_vector_type(8)));

static __device__ __forceinline__ unsigned short f2bf(float f) {
    unsigned u = __builtin_bit_cast(unsigned, f);
    u = (u + 0x7fffu + ((u >> 16) & 1u)) >> 16;
    return (unsigned short)u;
}

// ---------------- K0: cnorm + (-2*codebook) bf16 fragment-ordered ----------------
// cbfrag unit u = ((chunk*2 + cf)*8 + ks)*64 + lane; lane holds
// A[row = cf*16 + (lane&15)][k = ks*32 + (lane>>4)*8 + j], j=0..7, value -2*cb.
__global__ __launch_bounds__(64) void k0_prep(const float* __restrict__ cb,
                                              float* __restrict__ cnorm,
                                              s16x8* __restrict__ cbfrag) {
    const int code = blockIdx.x;
    const int l = threadIdx.x;
    const float4* cb4 = (const float4*)cb;
    const float4 v = cb4[code * 64 + l];
    float nrm = v.x * v.x + v.y * v.y + v.z * v.z + v.w * v.w;
    #pragma unroll
    for (int off = 1; off < 64; off <<= 1) nrm += __shfl_xor(nrm, off);
    if (l == 0) cnorm[code] = nrm;
    if (l < 32) {
        const float4 x0 = cb4[code * 64 + l * 2];
        const float4 x1 = cb4[code * 64 + l * 2 + 1];
        s16x8 f;
        f[0] = (short)f2bf(-2.f * x0.x); f[1] = (short)f2bf(-2.f * x0.y);
        f[2] = (short)f2bf(-2.f * x0.z); f[3] = (short)f2bf(-2.f * x0.w);
        f[4] = (short)f2bf(-2.f * x1.x); f[5] = (short)f2bf(-2.f * x1.y);
        f[6] = (short)f2bf(-2.f * x1.z); f[7] = (short)f2bf(-2.f * x1.w);
        const int cc = code >> 5, cf = (code >> 4) & 1, r16 = code & 15;
        const int ks = l >> 2, g = l & 3;
        cbfrag[((cc * 2 + cf) * 8 + ks) * 64 + g * 16 + r16] = f;
    }
}

// ---------------- K1 ----------------
__global__ __attribute__((amdgpu_waves_per_eu(2)))
__launch_bounds__(512) void k1_main(const float* __restrict__ z,
                                    const float* __restrict__ cbf,
                                    const float* __restrict__ cnorm,
                                    const s16x8* __restrict__ cbfrag,
                                    float* __restrict__ out,
                                    float* __restrict__ part) {
    __shared__ __align__(16) float zqbuf[32 * 260];
    __shared__ float encl[8][32];
    __shared__ unsigned idxl[128];
    __shared__ float red[8];

    const int t = threadIdx.x;
    const int w = t >> 6, l = t & 63;
    const int mg = w >> 1, nh = w & 1;          // M-group 0..3, N-half 0..1
    const int col = l & 15, g = l >> 4, gc4 = g * 4;
    const int b = blockIdx.x;
    const int bimg = b >> 3;
    const int hw0 = (b & 7) << 7;               // 128 positions per block
    const float* zp = z + bimg * 262144 + hw0 + mg * 32;

    // ---- z -> bf16 B-fragments (32 rows per wave) + z^2 partial ----
    float z2 = 0.f;
    s16x8 zf[2][8];
    #pragma unroll
    for (int pf = 0; pf < 2; ++pf) {
        const int p = pf * 16 + col;
        #pragma unroll
        for (int ks = 0; ks < 8; ++ks) {
            const float* src = zp + (ks * 32 + g * 8) * 1024 + p;
            s16x8 f;
            #pragma unroll
            for (int j = 0; j < 8; ++j) {
                const float v = src[j * 1024];
                z2 += v * v;
                f[j] = (short)f2bf(v);
            }
            zf[pf][ks] = f;
        }
    }

    float menc[2];
    menc[0] = __builtin_bit_cast(float, 0x7F7FFC00u);
    menc[1] = __builtin_bit_cast(float, 0x7F7FFC00u);

    const int cb_off = nh * 512;                // this wave's code base
    const s16x8* pbase = cbfrag + (nh * 16) * 1024 + l;
    s16x8 A0[16], A1[16];
    #pragma unroll
    for (int u = 0; u < 16; ++u) A0[u] = pbase[u * 64];

#define BODY(CUR, NXT, c) do {                                                   \
    if ((c) + 1 < 16) {                                                          \
        const s16x8* pn = pbase + ((c) + 1) * 1024;                              \
        _Pragma("unroll") for (int u = 0; u < 16; ++u) NXT[u] = pn[u * 64];      \
    }                                                                            \
    f32x4 a00 = {0.f,0.f,0.f,0.f}, a01 = {0.f,0.f,0.f,0.f};                      \
    f32x4 a10 = {0.f,0.f,0.f,0.f}, a11 = {0.f,0.f,0.f,0.f};                      \
    _Pragma("unroll") for (int ks = 0; ks < 8; ++ks) {                           \
        a00 = __builtin_amdgcn_mfma_f32_16x16x32_bf16(CUR[ks],     zf[0][ks], a00, 0, 0, 0); \
        a01 = __builtin_amdgcn_mfma_f32_16x16x32_bf16(CUR[ks],     zf[1][ks], a01, 0, 0, 0); \
        a10 = __builtin_amdgcn_mfma_f32_16x16x32_bf16(CUR[8 + ks], zf[0][ks], a10, 0, 0, 0); \
        a11 = __builtin_amdgcn_mfma_f32_16x16x32_bf16(CUR[8 + ks], zf[1][ks], a11, 0, 0, 0); \
    }                                                                            \
    {                                                                            \
        const f32x4 cn0 = *(const f32x4*)(cnorm + cb_off + (c) * 32 + gc4);      \
        const f32x4 cn1 = *(const f32x4*)(cnorm + cb_off + (c) * 32 + 16 + gc4); \
        _Pragma("unroll") for (int r = 0; r < 4; ++r) {                          \
            const unsigned code0 = (unsigned)(cb_off + (c) * 32 + gc4 + r);      \
            float s;                                                             \
            unsigned e;                                                          \
            s = a00[r] + cn0[r];                                                 \
            e = (__builtin_bit_cast(unsigned, s) & 0xFFFFFC00u) | code0;         \
            menc[0] = fminf(menc[0], __builtin_bit_cast(float, e));              \
            s = a01[r] + cn0[r];                                                 \
            e = (__builtin_bit_cast(unsigned, s) & 0xFFFFFC00u) | code0;         \
            menc[1] = fminf(menc[1], __builtin_bit_cast(float, e));              \
            s = a10[r] + cn1[r];                                                 \
            e = (__builtin_bit_cast(unsigned, s) & 0xFFFFFC00u) | (code0 + 16u); \
            menc[0] = fminf(menc[0], __builtin_bit_cast(float, e));              \
            s = a11[r] + cn1[r];                                                 \
            e = (__builtin_bit_cast(unsigned, s) & 0xFFFFFC00u) | (code0 + 16u); \
            menc[1] = fminf(menc[1], __builtin_bit_cast(float, e));              \
        }                                                                        \
    }                                                                            \
    __builtin_amdgcn_s_barrier();                                                \
} while (0)

    #pragma unroll 1
    for (int c2 = 0; c2 < 16; c2 += 2) {
        BODY(A0, A1, c2);
        BODY(A1, A0, c2 + 1);
    }
#undef BODY

    // merge encoded argmin across the 4 g-groups (same position column)
    #pragma unroll
    for (int pf = 0; pf < 2; ++pf) {
        menc[pf] = fminf(menc[pf], __shfl_xor(menc[pf], 16));
        menc[pf] = fminf(menc[pf], __shfl_xor(menc[pf], 32));
    }
    if (l < 16) {
        encl[w][l]      = menc[0];
        encl[w][16 + l] = menc[1];
    }
    __syncthreads();

    // final per-row merge across N-halves (threads 0..127 = block rows)
    float myS = 0.f;
    if (t < 128) {
        const int mg2 = t >> 5, rr = t & 31;
        const float e = fminf(encl[mg2 * 2][rr], encl[mg2 * 2 + 1][rr]);
        const unsigned eu = __builtin_bit_cast(unsigned, e);
        idxl[t] = eu & 0x3FFu;
        myS = __builtin_bit_cast(float, eu & 0xFFFFFC00u);
    }

    // loss partial: sum z^2 (N-half-0 waves) + sum minS (threads 0..127)
    float v = myS + ((nh == 0) ? z2 : 0.f);
    #pragma unroll
    for (int off = 1; off < 64; off <<= 1) v += __shfl_xor(v, off);
    if (l == 0) red[w] = v;
    __syncthreads();
    if (t == 0)
        part[b] = red[0] + red[1] + red[2] + red[3] + red[4] + red[5] + red[6] + red[7];

    // ---- z_q epilogue: gather codebook rows -> LDS transpose -> NCHW ----
    const float4* cb4 = (const float4*)cbf;
    for (int h = 0; h < 4; ++h) {
        __syncthreads();
        #pragma unroll
        for (int i = 0; i < 4; ++i) {
            const int flat = i * 512 + t;        // [0,2048)
            const int p = flat >> 6;             // row 0..31
            const int q = flat & 63;             // float4 index
            const unsigned code = idxl[h * 32 + p];
            *(float4*)&zqbuf[p * 260 + q * 4] = cb4[code * 64 + q];
        }
        __syncthreads();
        const int p = t & 31, c0 = t >> 5;       // c0 0..15
        float* ob = out + bimg * 262144 + hw0 + h * 32 + p;
        #pragma unroll
        for (int cc = 0; cc < 16; ++cc) {
            const int ch = c0 + cc * 16;
            ob[ch * 1024] = zqbuf[p * 260 + ch];
        }
    }
}

// ---------------- K2: deterministic final reduce -> loss ----------------
__global__ __launch_bounds__(256) void k2_fin(const float* __restrict__ part,
                                              float* __restrict__ out) {
    __shared__ float red[256];
    const int t = threadIdx.x;
    red[t] = part[t];
    __syncthreads();
    #pragma unroll
    for (int off = 128; off > 0; off >>= 1) {
        if (t < off) red[t] += red[t + off];
        __syncthreads();
    }
    if (t == 0) out[8388608] = 1.25f * red[0] / 8388608.f;
}

extern "C" void kernel_launch(void* const* d_in, const int* in_sizes, int n_in,
                              void* d_out, int out_size, void* d_ws, size_t ws_size,
                              hipStream_t stream) {
    const float* z  = (const float*)d_in[0];
    const float* cb = (const float*)d_in[1];
    float* out = (float*)d_out;
    unsigned char* ws = (unsigned char*)d_ws;
    float* cnorm = (float*)(ws + WS_CNORM_OFF);
    s16x8* cbfrag = (s16x8*)(ws + WS_CB_OFF);
    float* part = (float*)(ws + WS_PART_OFF);

    hipLaunchKernelGGL(k0_prep, dim3(NCODE), dim3(64), 0, stream, cb, cnorm, cbfrag);
    hipLaunchKernelGGL(k1_main, dim3(256), dim3(512), 0, stream,
                       z, cb, cnorm, cbfrag, out, part);
    hipLaunchKernelGGL(k2_fin, dim3(1), dim3(256), 0, stream, part, out);
}

// Round 6
// 54.779 us; speedup vs baseline: 1.4418x; 1.4418x over previous
//
#include <hip/hip_runtime.h>
#include <hip/hip_bf16.h>
#include <stdint.h>

// VQ: z (32,256,32,32) f32 NCHW, codebook (1024,256) f32
// out: z_q (8388608 f32, NCHW) + commit_loss (1 f32 at out[8388608])
//
// R6: R2's proven register structure (188 VGPR, no spill, plain
// __launch_bounds__(256)) at DOUBLE the legal occupancy: 512 blocks x 256
// thr; wave = (M-group of 32 rows) x (codebook-half of 512 codes).
// 188 VGPR allows 2 waves/SIMD; R2's 256-block grid used only 1 block/CU.
// 2 independent blocks/CU cover MFMA dep-chains + prefetch latency.
// ks-major 4-chain MFMA interleave. Encoded-float argmin
// (S & ~0x3FF) | code. Loss = sum(z^2) + sum(minS). Fused z_q epilogue.

#define NPOS   32768
#define NCODE  1024
#define DIM    256

#define WS_CNORM_OFF 0
#define WS_CB_OFF    4096
#define WS_PART_OFF  (4096 + 1024 * 512)   // after 512KB cbfrag

typedef float f32x4 __attribute__((ext_vector_type(4)));
typedef short s16x8 __attribute__((ext_vector_type(8)));

static __device__ __forceinline__ unsigned short f2bf(float f) {
    unsigned u = __builtin_bit_cast(unsigned, f);
    u = (u + 0x7fffu + ((u >> 16) & 1u)) >> 16;
    return (unsigned short)u;
}

// ---------------- K0: cnorm + (-2*codebook) bf16 fragment-ordered ----------------
// cbfrag unit u = ((cc*2 + cf)*8 + ks)*64 + lane; lane holds
// A[row = cf*16 + (lane&15)][k = ks*32 + (lane>>4)*8 + j], j=0..7, value -2*cb.
__global__ __launch_bounds__(64) void k0_prep(const float* __restrict__ cb,
                                              float* __restrict__ cnorm,
                                              s16x8* __restrict__ cbfrag) {
    const int code = blockIdx.x;
    const int l = threadIdx.x;
    const float4* cb4 = (const float4*)cb;
    const float4 v = cb4[code * 64 + l];
    float nrm = v.x * v.x + v.y * v.y + v.z * v.z + v.w * v.w;
    #pragma unroll
    for (int off = 1; off < 64; off <<= 1) nrm += __shfl_xor(nrm, off);
    if (l == 0) cnorm[code] = nrm;
    if (l < 32) {
        const float4 x0 = cb4[code * 64 + l * 2];
        const float4 x1 = cb4[code * 64 + l * 2 + 1];
        s16x8 f;
        f[0] = (short)f2bf(-2.f * x0.x); f[1] = (short)f2bf(-2.f * x0.y);
        f[2] = (short)f2bf(-2.f * x0.z); f[3] = (short)f2bf(-2.f * x0.w);
        f[4] = (short)f2bf(-2.f * x1.x); f[5] = (short)f2bf(-2.f * x1.y);
        f[6] = (short)f2bf(-2.f * x1.z); f[7] = (short)f2bf(-2.f * x1.w);
        const int cc = code >> 5, cf = (code >> 4) & 1, r16 = code & 15;
        const int ks = l >> 2, g = l & 3;
        cbfrag[((cc * 2 + cf) * 8 + ks) * 64 + g * 16 + r16] = f;
    }
}

// ---------------- K1 ----------------
__global__ __launch_bounds__(256) void k1_main(const float* __restrict__ z,
                                               const float* __restrict__ cbf,
                                               const float* __restrict__ cnorm,
                                               const s16x8* __restrict__ cbfrag,
                                               float* __restrict__ out,
                                               float* __restrict__ part) {
    __shared__ __align__(16) float zqbuf[32 * 260];
    __shared__ float encl[4][32];
    __shared__ unsigned idxl[64];
    __shared__ float red[4];

    const int t = threadIdx.x;
    const int w = t >> 6, l = t & 63;
    const int mg = w >> 1, nh = w & 1;          // M-group 0..1, N-half 0..1
    const int col = l & 15, g = l >> 4, gc4 = g * 4;
    const int b = blockIdx.x;
    const int bimg = b >> 4;                    // 16 blocks per image
    const int hw0 = (b & 15) << 6;              // 64 positions per block
    const float* zp = z + bimg * 262144 + hw0 + mg * 32;

    // ---- z -> bf16 B-fragments (32 rows per wave) + z^2 partial ----
    float z2 = 0.f;
    s16x8 zf[2][8];
    #pragma unroll
    for (int pf = 0; pf < 2; ++pf) {
        const int p = pf * 16 + col;
        #pragma unroll
        for (int ks = 0; ks < 8; ++ks) {
            const float* src = zp + (ks * 32 + g * 8) * 1024 + p;
            s16x8 f;
            #pragma unroll
            for (int j = 0; j < 8; ++j) {
                const float v = src[j * 1024];
                z2 += v * v;
                f[j] = (short)f2bf(v);
            }
            zf[pf][ks] = f;
        }
    }

    float menc[2];
    menc[0] = __builtin_bit_cast(float, 0x7F7FFC00u);
    menc[1] = __builtin_bit_cast(float, 0x7F7FFC00u);

    const int cb_off = nh * 512;                // this wave's code base
    const s16x8* pbase = cbfrag + (nh * 16) * 1024 + l;
    s16x8 A0[16], A1[16];
    #pragma unroll
    for (int u = 0; u < 16; ++u) A0[u] = pbase[u * 64];

#define BODY(CUR, NXT, c) do {                                                   \
    if ((c) + 1 < 16) {                                                          \
        const s16x8* pn = pbase + ((c) + 1) * 1024;                              \
        _Pragma("unroll") for (int u = 0; u < 16; ++u) NXT[u] = pn[u * 64];      \
    }                                                                            \
    f32x4 a00 = {0.f,0.f,0.f,0.f}, a01 = {0.f,0.f,0.f,0.f};                      \
    f32x4 a10 = {0.f,0.f,0.f,0.f}, a11 = {0.f,0.f,0.f,0.f};                      \
    _Pragma("unroll") for (int ks = 0; ks < 8; ++ks) {                           \
        a00 = __builtin_amdgcn_mfma_f32_16x16x32_bf16(CUR[ks],     zf[0][ks], a00, 0, 0, 0); \
        a01 = __builtin_amdgcn_mfma_f32_16x16x32_bf16(CUR[ks],     zf[1][ks], a01, 0, 0, 0); \
        a10 = __builtin_amdgcn_mfma_f32_16x16x32_bf16(CUR[8 + ks], zf[0][ks], a10, 0, 0, 0); \
        a11 = __builtin_amdgcn_mfma_f32_16x16x32_bf16(CUR[8 + ks], zf[1][ks], a11, 0, 0, 0); \
    }                                                                            \
    {                                                                            \
        const f32x4 cn0 = *(const f32x4*)(cnorm + cb_off + (c) * 32 + gc4);      \
        const f32x4 cn1 = *(const f32x4*)(cnorm + cb_off + (c) * 32 + 16 + gc4); \
        _Pragma("unroll") for (int r = 0; r < 4; ++r) {                          \
            const unsigned code0 = (unsigned)(cb_off + (c) * 32 + gc4 + r);      \
            float s;                                                             \
            unsigned e;                                                          \
            s = a00[r] + cn0[r];                                                 \
            e = (__builtin_bit_cast(unsigned, s) & 0xFFFFFC00u) | code0;         \
            menc[0] = fminf(menc[0], __builtin_bit_cast(float, e));              \
            s = a01[r] + cn0[r];                                                 \
            e = (__builtin_bit_cast(unsigned, s) & 0xFFFFFC00u) | code0;         \
            menc[1] = fminf(menc[1], __builtin_bit_cast(float, e));              \
            s = a10[r] + cn1[r];                                                 \
            e = (__builtin_bit_cast(unsigned, s) & 0xFFFFFC00u) | (code0 + 16u); \
            menc[0] = fminf(menc[0], __builtin_bit_cast(float, e));              \
            s = a11[r] + cn1[r];                                                 \
            e = (__builtin_bit_cast(unsigned, s) & 0xFFFFFC00u) | (code0 + 16u); \
            menc[1] = fminf(menc[1], __builtin_bit_cast(float, e));              \
        }                                                                        \
    }                                                                            \
    __builtin_amdgcn_s_barrier();                                                \
} while (0)

    #pragma unroll 1
    for (int c2 = 0; c2 < 16; c2 += 2) {
        BODY(A0, A1, c2);
        BODY(A1, A0, c2 + 1);
    }
#undef BODY

    // merge encoded argmin across the 4 g-groups (same position column)
    #pragma unroll
    for (int pf = 0; pf < 2; ++pf) {
        menc[pf] = fminf(menc[pf], __shfl_xor(menc[pf], 16));
        menc[pf] = fminf(menc[pf], __shfl_xor(menc[pf], 32));
    }
    if (l < 16) {
        encl[w][l]      = menc[0];
        encl[w][16 + l] = menc[1];
    }
    __syncthreads();

    // final per-row merge across N-halves (threads 0..63 = block rows)
    float myS = 0.f;
    if (t < 64) {
        const int mg2 = t >> 5, rr = t & 31;
        const float e = fminf(encl[mg2 * 2][rr], encl[mg2 * 2 + 1][rr]);
        const unsigned eu = __builtin_bit_cast(unsigned, e);
        idxl[t] = eu & 0x3FFu;
        myS = __builtin_bit_cast(float, eu & 0xFFFFFC00u);
    }

    // loss partial: sum z^2 (N-half-0 waves only) + sum minS (threads 0..63)
    float v = myS + ((nh == 0) ? z2 : 0.f);
    #pragma unroll
    for (int off = 1; off < 64; off <<= 1) v += __shfl_xor(v, off);
    if (l == 0) red[w] = v;
    __syncthreads();
    if (t == 0) part[b] = red[0] + red[1] + red[2] + red[3];

    // ---- z_q epilogue: gather codebook rows -> LDS transpose -> NCHW ----
    const float4* cb4 = (const float4*)cbf;
    for (int h = 0; h < 2; ++h) {
        __syncthreads();
        #pragma unroll
        for (int i = 0; i < 8; ++i) {
            const int flat = i * 256 + t;        // [0,2048)
            const int p = flat >> 6;             // row 0..31
            const int q = flat & 63;             // float4 index
            const unsigned code = idxl[h * 32 + p];
            *(float4*)&zqbuf[p * 260 + q * 4] = cb4[code * 64 + q];
        }
        __syncthreads();
        const int p = t & 31, c0 = t >> 5;       // c0 0..7
        float* ob = out + bimg * 262144 + hw0 + h * 32 + p;
        #pragma unroll
        for (int cc = 0; cc < 32; ++cc) {
            const int ch = c0 + cc * 8;
            ob[ch * 1024] = zqbuf[p * 260 + ch];
        }
    }
}

// ---------------- K2: deterministic final reduce -> loss ----------------
__global__ __launch_bounds__(256) void k2_fin(const float* __restrict__ part,
                                              float* __restrict__ out) {
    __shared__ float red[256];
    const int t = threadIdx.x;
    red[t] = part[t] + part[t + 256];
    __syncthreads();
    #pragma unroll
    for (int off = 128; off > 0; off >>= 1) {
        if (t < off) red[t] += red[t + off];
        __syncthreads();
    }
    if (t == 0) out[8388608] = 1.25f * red[0] / 8388608.f;
}

extern "C" void kernel_launch(void* const* d_in, const int* in_sizes, int n_in,
                              void* d_out, int out_size, void* d_ws, size_t ws_size,
                              hipStream_t stream) {
    const float* z  = (const float*)d_in[0];
    const float* cb = (const float*)d_in[1];
    float* out = (float*)d_out;
    unsigned char* ws = (unsigned char*)d_ws;
    float* cnorm = (float*)(ws + WS_CNORM_OFF);
    s16x8* cbfrag = (s16x8*)(ws + WS_CB_OFF);
    float* part = (float*)(ws + WS_PART_OFF);

    hipLaunchKernelGGL(k0_prep, dim3(NCODE), dim3(64), 0, stream, cb, cnorm, cbfrag);
    hipLaunchKernelGGL(k1_main, dim3(512), dim3(256), 0, stream,
                       z, cb, cnorm, cbfrag, out, part);
    hipLaunchKernelGGL(k2_fin, dim3(1), dim3(256), 0, stream, part, out);
}